// Round 1
// baseline (3592.683 us; speedup 1.0000x reference)
//
#include <hip/hip_runtime.h>

#define LL 12
#define NN 2048
#define KK 8
#define SS 4
#define HH 256

__device__ __forceinline__ float sigmoidf(float x) { return 1.f / (1.f + expf(-x)); }

// ---------------- Kernel 1: x = concat_s(E[tok_s]) @ lin_W + lin_b ----------------
// rows m in [0, 2*L*N); 8 rows/block; 256 threads; thread t owns output column t.
__global__ __launch_bounds__(256) void k_embed_lin(
    const int* __restrict__ tok1, const int* __restrict__ tok2,
    const float* __restrict__ E, const float* __restrict__ linW,
    const float* __restrict__ linb, float* __restrict__ xout)
{
    __shared__ __align__(16) float a[8][SS * HH];   // 32 KB
    const int t = threadIdx.x;
    const int m0 = blockIdx.x * 8;
    for (int rr = 0; rr < 8; ++rr) {
        const int m = m0 + rr;
        const int e = m / (LL * NN);
        const int r = m - e * (LL * NN);           // l*N + n
        const int* tok = (e == 0 ? tok1 : tok2) + (size_t)r * SS;
        #pragma unroll
        for (int s = 0; s < SS; ++s) {
            const int tk = tok[s];
            a[rr][s * HH + t] = E[(size_t)tk * HH + t];
        }
    }
    __syncthreads();
    float acc[8];
    #pragma unroll
    for (int rr = 0; rr < 8; ++rr) acc[rr] = 0.f;
    for (int k = 0; k < SS * HH; k += 4) {
        const float b0 = linW[(size_t)(k + 0) * HH + t];
        const float b1 = linW[(size_t)(k + 1) * HH + t];
        const float b2 = linW[(size_t)(k + 2) * HH + t];
        const float b3 = linW[(size_t)(k + 3) * HH + t];
        #pragma unroll
        for (int rr = 0; rr < 8; ++rr) {
            const float4 av = *reinterpret_cast<const float4*>(&a[rr][k]);
            acc[rr] = fmaf(av.x, b0, acc[rr]);
            acc[rr] = fmaf(av.y, b1, acc[rr]);
            acc[rr] = fmaf(av.z, b2, acc[rr]);
            acc[rr] = fmaf(av.w, b3, acc[rr]);
        }
    }
    const float bias = linb[t];
    for (int rr = 0; rr < 8; ++rr)
        xout[(size_t)(m0 + rr) * HH + t] = acc[rr] + bias;
}

// ---------------- Kernel 2: one scan step, batch = 2*N rows (both encoders) ----------------
// 4 rows/block; 256 threads; thread t owns output column t.
__global__ __launch_bounds__(256) void k_step(
    const float* __restrict__ x,      // [2][L][N][H]
    const int* __restrict__ idx1,     // [L][N][K]
    const int* __restrict__ idx2,
    const float* __restrict__ WW, const float* __restrict__ Wb,     // (H,4H),(4H) gates f,i,u,o
    const float* __restrict__ UfW, const float* __restrict__ Ufb,   // (H,H),(H)
    const float* __restrict__ UiW, const float* __restrict__ Uib,   // (H,3H),(3H) i,u,o
    const float* __restrict__ hprev, const float* __restrict__ cprev, // [2N][H]
    float* __restrict__ hnext, float* __restrict__ cnext,             // [2N][H]
    const int l)
{
    __shared__ __align__(16) float xl[4][HH];      // 4 KB
    __shared__ __align__(16) float hm[4 * KK][HH]; // 32 KB  (pre-masked gathered h)
    __shared__ __align__(16) float hsum[4][HH];    // 4 KB
    __shared__ int child[4][KK];
    const int t = threadIdx.x;
    const int g0 = blockIdx.x * 4;

    #pragma unroll
    for (int rr = 0; rr < 4; ++rr) {
        const int g = g0 + rr;
        const int e = g >> 11;
        const int n = g & (NN - 1);
        xl[rr][t] = x[((size_t)e * LL * NN + (size_t)l * NN + n) * HH + t];
        if (t < KK) {
            const int* idxp = (e == 0 ? idx1 : idx2);
            const int il = idxp[((size_t)l * NN + n) * KK + t];
            // il==-1 (masked) and il==0 (zero row) both contribute exactly 0
            child[rr][t] = (il >= 1) ? (e * NN + il - 1) : -1;
        }
    }
    __syncthreads();

    // gather children h (pre-masked) and accumulate h_sum
    #pragma unroll
    for (int rr = 0; rr < 4; ++rr) {
        float s = 0.f;
        #pragma unroll
        for (int k = 0; k < KK; ++k) {
            const int ch = child[rr][k];
            float v = 0.f;
            if (ch >= 0) v = hprev[(size_t)ch * HH + t];
            hm[rr * KK + k][t] = v;
            s += v;
        }
        hsum[rr][t] = s;
    }
    __syncthreads();

    // phase 1: Wx = xl @ WW + Wb
    float wf[4] = {0,0,0,0}, wi[4] = {0,0,0,0}, wu[4] = {0,0,0,0}, wo[4] = {0,0,0,0};
    for (int k = 0; k < HH; k += 4) {
        float4 xv[4];
        #pragma unroll
        for (int rr = 0; rr < 4; ++rr) xv[rr] = *reinterpret_cast<const float4*>(&xl[rr][k]);
        #pragma unroll
        for (int kk = 0; kk < 4; ++kk) {
            const size_t row = (size_t)(k + kk) * (4 * HH);
            const float bf_ = WW[row + 0 * HH + t];
            const float bi_ = WW[row + 1 * HH + t];
            const float bu_ = WW[row + 2 * HH + t];
            const float bo_ = WW[row + 3 * HH + t];
            #pragma unroll
            for (int rr = 0; rr < 4; ++rr) {
                const float av = reinterpret_cast<const float*>(&xv[rr])[kk];
                wf[rr] = fmaf(av, bf_, wf[rr]);
                wi[rr] = fmaf(av, bi_, wi[rr]);
                wu[rr] = fmaf(av, bu_, wu[rr]);
                wo[rr] = fmaf(av, bo_, wo[rr]);
            }
        }
    }
    {
        const float bf_ = Wb[0 * HH + t], bi_ = Wb[1 * HH + t];
        const float bu_ = Wb[2 * HH + t], bo_ = Wb[3 * HH + t];
        #pragma unroll
        for (int rr = 0; rr < 4; ++rr) { wf[rr] += bf_; wi[rr] += bi_; wu[rr] += bu_; wo[rr] += bo_; }
    }

    // phase 2: fk_pre = hm @ UfW   (32 child rows), then bf = sum_k sigmoid(.)*c
    float fa[32];
    #pragma unroll
    for (int j = 0; j < 32; ++j) fa[j] = 0.f;
    for (int k = 0; k < HH; k += 4) {
        const float b0 = UfW[(size_t)(k + 0) * HH + t];
        const float b1 = UfW[(size_t)(k + 1) * HH + t];
        const float b2 = UfW[(size_t)(k + 2) * HH + t];
        const float b3 = UfW[(size_t)(k + 3) * HH + t];
        #pragma unroll
        for (int j = 0; j < 32; ++j) {
            const float4 hv = *reinterpret_cast<const float4*>(&hm[j][k]);
            fa[j] = fmaf(hv.x, b0, fa[j]);
            fa[j] = fmaf(hv.y, b1, fa[j]);
            fa[j] = fmaf(hv.z, b2, fa[j]);
            fa[j] = fmaf(hv.w, b3, fa[j]);
        }
    }
    const float ufb = Ufb[t];
    float bfa[4] = {0,0,0,0};
    #pragma unroll
    for (int rr = 0; rr < 4; ++rr) {
        #pragma unroll
        for (int k = 0; k < KK; ++k) {
            const int ch = child[rr][k];      // wave-uniform branch
            if (ch >= 0) {
                const float cv = cprev[(size_t)ch * HH + t];
                const float fk = sigmoidf(fa[rr * KK + k] + wf[rr] + ufb);
                bfa[rr] = fmaf(fk, cv, bfa[rr]);
            }
        }
    }

    // phase 3: iuo = hsum @ UiW
    float ai[4] = {0,0,0,0}, au[4] = {0,0,0,0}, ao[4] = {0,0,0,0};
    for (int k = 0; k < HH; k += 4) {
        float4 sv[4];
        #pragma unroll
        for (int rr = 0; rr < 4; ++rr) sv[rr] = *reinterpret_cast<const float4*>(&hsum[rr][k]);
        #pragma unroll
        for (int kk = 0; kk < 4; ++kk) {
            const size_t row = (size_t)(k + kk) * (3 * HH);
            const float bi_ = UiW[row + 0 * HH + t];
            const float bu_ = UiW[row + 1 * HH + t];
            const float bo_ = UiW[row + 2 * HH + t];
            #pragma unroll
            for (int rr = 0; rr < 4; ++rr) {
                const float av = reinterpret_cast<const float*>(&sv[rr])[kk];
                ai[rr] = fmaf(av, bi_, ai[rr]);
                au[rr] = fmaf(av, bu_, au[rr]);
                ao[rr] = fmaf(av, bo_, ao[rr]);
            }
        }
    }

    // phase 4: gates + state update
    const float bib = Uib[0 * HH + t], bub = Uib[1 * HH + t], bob = Uib[2 * HH + t];
    #pragma unroll
    for (int rr = 0; rr < 4; ++rr) {
        const float ig = sigmoidf(ai[rr] + bib + wi[rr]);
        const float ug = tanhf(au[rr] + bub + wu[rr]);
        const float og = sigmoidf(ao[rr] + bob + wo[rr]);
        const float nc = fmaf(ig, ug, bfa[rr]);
        const float nh = og * tanhf(nc);
        hnext[(size_t)(g0 + rr) * HH + t] = nh;
        cnext[(size_t)(g0 + rr) * HH + t] = nc;
    }
}

// ---------------- Kernel 3: siamese head ----------------
// h1=h_last[0]+x[0][L-1]; h2=h_last[1]+x[1][L-1]; tanh(|h1-h2|@dW+db)@oW+ob -> softmax
__global__ __launch_bounds__(256) void k_final(
    const float* __restrict__ hlast,   // [2N][H]
    const float* __restrict__ x,       // [2][L][N][H]
    const float* __restrict__ dW, const float* __restrict__ db,  // (H,512),(512)
    const float* __restrict__ oW, const float* __restrict__ ob,  // (512,2),(2)
    float* __restrict__ out)           // [N][2]
{
    __shared__ __align__(16) float ad[8][HH];    // 8 KB
    __shared__ __align__(16) float xx[8][512];   // 16 KB
    const int t = threadIdx.x;
    const int n0 = blockIdx.x * 8;
    const size_t xoff1 = (size_t)(LL - 1) * NN * HH;
    const size_t xoff2 = (size_t)LL * NN * HH + xoff1;
    #pragma unroll
    for (int rr = 0; rr < 8; ++rr) {
        const int n = n0 + rr;
        const float h1 = hlast[(size_t)n * HH + t] + x[xoff1 + (size_t)n * HH + t];
        const float h2 = hlast[((size_t)NN + n) * HH + t] + x[xoff2 + (size_t)n * HH + t];
        ad[rr][t] = fabsf(h1 - h2);
    }
    __syncthreads();
    float a0[8], a1[8];
    #pragma unroll
    for (int rr = 0; rr < 8; ++rr) { a0[rr] = 0.f; a1[rr] = 0.f; }
    for (int k = 0; k < HH; k += 4) {
        #pragma unroll
        for (int kk = 0; kk < 4; ++kk) {
            const float b0 = dW[(size_t)(k + kk) * 512 + t];
            const float b1 = dW[(size_t)(k + kk) * 512 + 256 + t];
            #pragma unroll
            for (int rr = 0; rr < 8; ++rr) {
                const float av = ad[rr][k + kk];
                a0[rr] = fmaf(av, b0, a0[rr]);
                a1[rr] = fmaf(av, b1, a1[rr]);
            }
        }
    }
    const float db0 = db[t], db1 = db[256 + t];
    #pragma unroll
    for (int rr = 0; rr < 8; ++rr) {
        xx[rr][t] = tanhf(a0[rr] + db0);
        xx[rr][256 + t] = tanhf(a1[rr] + db1);
    }
    __syncthreads();
    const int w = t >> 6, lane = t & 63;
    for (int rr = w; rr < 8; rr += 4) {
        float p0 = 0.f, p1 = 0.f;
        for (int k = lane; k < 512; k += 64) {
            const float xv = xx[rr][k];
            p0 = fmaf(xv, oW[2 * k + 0], p0);
            p1 = fmaf(xv, oW[2 * k + 1], p1);
        }
        #pragma unroll
        for (int off = 32; off > 0; off >>= 1) {
            p0 += __shfl_down(p0, off);
            p1 += __shfl_down(p1, off);
        }
        if (lane == 0) {
            const float l0 = p0 + ob[0], l1 = p1 + ob[1];
            const float mx = fmaxf(l0, l1);
            const float e0 = expf(l0 - mx), e1 = expf(l1 - mx);
            const float inv = 1.f / (e0 + e1);
            out[(size_t)(n0 + rr) * 2 + 0] = e0 * inv;
            out[(size_t)(n0 + rr) * 2 + 1] = e1 * inv;
        }
    }
}

extern "C" void kernel_launch(void* const* d_in, const int* in_sizes, int n_in,
                              void* d_out, int out_size, void* d_ws, size_t ws_size,
                              hipStream_t stream) {
    (void)in_sizes; (void)n_in; (void)out_size; (void)ws_size;
    const int*   tok1 = (const int*)d_in[0];
    const int*   idx1 = (const int*)d_in[1];
    const int*   tok2 = (const int*)d_in[2];
    const int*   idx2 = (const int*)d_in[3];
    const float* E    = (const float*)d_in[4];
    const float* linW = (const float*)d_in[5];
    const float* linb = (const float*)d_in[6];
    const float* UfW  = (const float*)d_in[7];
    const float* Ufb  = (const float*)d_in[8];
    const float* UiW  = (const float*)d_in[9];
    const float* Uib  = (const float*)d_in[10];
    const float* WW   = (const float*)d_in[11];
    const float* Wb   = (const float*)d_in[12];
    const float* dW   = (const float*)d_in[13];
    const float* db   = (const float*)d_in[14];
    const float* oW   = (const float*)d_in[15];
    const float* ob   = (const float*)d_in[16];
    float* out = (float*)d_out;

    float* ws   = (float*)d_ws;
    float* xbuf = ws;                                   // 2*L*N*H
    float* h0   = xbuf + (size_t)2 * LL * NN * HH;      // 2*N*H
    float* c0   = h0 + (size_t)2 * NN * HH;
    float* h1   = c0 + (size_t)2 * NN * HH;
    float* c1   = h1 + (size_t)2 * NN * HH;

    k_embed_lin<<<(2 * LL * NN) / 8, 256, 0, stream>>>(tok1, tok2, E, linW, linb, xbuf);

    float* hc = h0; float* cc = c0; float* hn = h1; float* cn = c1;
    for (int l = 0; l < LL; ++l) {
        // l==0: idx[0] is all -1, so hprev/cprev are never read (poison-safe)
        k_step<<<(2 * NN) / 4, 256, 0, stream>>>(xbuf, idx1, idx2, WW, Wb, UfW, Ufb,
                                                 UiW, Uib, hc, cc, hn, cn, l);
        float* th = hc; hc = hn; hn = th;
        float* tc = cc; cc = cn; cn = tc;
    }

    k_final<<<NN / 8, 256, 0, stream>>>(hc, xbuf, dW, db, oW, ob, out);
}

// Round 2
// 1318.709 us; speedup vs baseline: 2.7244x; 2.7244x over previous
//
#include <hip/hip_runtime.h>

#define LL 12
#define NN 2048
#define KK 8
#define SS 4
#define HH 256
#define LN (LL*NN)

typedef __bf16 bf16_t;
typedef __bf16 bf16x8 __attribute__((ext_vector_type(8)));
typedef float f32x4 __attribute__((ext_vector_type(4)));

__device__ __forceinline__ float sigmoidf_(float x) { return 1.f / (1.f + expf(-x)); }

// ---------------- converts: f32 (R,C) -> bf16 transposed (C,R) ----------------
__global__ __launch_bounds__(256) void k_cvt_t(const float* __restrict__ src,
                                               bf16_t* __restrict__ dst, int R, int C)
{
    const int i = blockIdx.x * 256 + threadIdx.x;
    if (i < R * C) {
        const int rr = i / C, cc = i - rr * C;
        dst[(size_t)cc * R + rr] = (bf16_t)src[i];
    }
}

// ---------------- generic MFMA GEMM body: C = A(bf16,MxK) @ Bt(bf16,NxK)^T + bias ----------------
// block = 256 threads = 4 waves (2x2), block tile 64x128, wave tile 32x64.
// A row remap: global_row = m0 + (m0>=a_thresh ? a_fix : 0) + local  (block-uniform).
__device__ __forceinline__ void gemm_body(
    const bf16_t* __restrict__ A, int lda,
    const bf16_t* __restrict__ Bt, int ldb,
    const float* __restrict__ bias,
    bf16_t* __restrict__ C, int ldc,
    int m0, int n0, int K, int a_thresh, int a_fix)
{
    const int t = threadIdx.x;
    const int lane = t & 63, w = t >> 6;
    const int wm = w >> 1, wn = w & 1;
    const int r = lane & 15, kg = lane >> 4;
    const int grow0 = m0 + (m0 >= a_thresh ? a_fix : 0);

    const bf16_t* ap0 = A + (size_t)(grow0 + wm * 32 + r) * lda + kg * 8;
    const bf16_t* ap1 = ap0 + (size_t)16 * lda;
    const bf16_t* bp0 = Bt + (size_t)(n0 + wn * 64 + r) * ldb + kg * 8;
    const bf16_t* bp1 = bp0 + (size_t)16 * ldb;
    const bf16_t* bp2 = bp1 + (size_t)16 * ldb;
    const bf16_t* bp3 = bp2 + (size_t)16 * ldb;

    const f32x4 zero = {0.f, 0.f, 0.f, 0.f};
    f32x4 acc[2][4];
    #pragma unroll
    for (int mi = 0; mi < 2; ++mi)
        #pragma unroll
        for (int ni = 0; ni < 4; ++ni) acc[mi][ni] = zero;

    for (int k0 = 0; k0 < K; k0 += 32) {
        const bf16x8 a0 = *(const bf16x8*)ap0;
        const bf16x8 a1 = *(const bf16x8*)ap1;
        const bf16x8 b0 = *(const bf16x8*)bp0;
        const bf16x8 b1 = *(const bf16x8*)bp1;
        const bf16x8 b2 = *(const bf16x8*)bp2;
        const bf16x8 b3 = *(const bf16x8*)bp3;
        acc[0][0] = __builtin_amdgcn_mfma_f32_16x16x32_bf16(a0, b0, acc[0][0], 0, 0, 0);
        acc[0][1] = __builtin_amdgcn_mfma_f32_16x16x32_bf16(a0, b1, acc[0][1], 0, 0, 0);
        acc[0][2] = __builtin_amdgcn_mfma_f32_16x16x32_bf16(a0, b2, acc[0][2], 0, 0, 0);
        acc[0][3] = __builtin_amdgcn_mfma_f32_16x16x32_bf16(a0, b3, acc[0][3], 0, 0, 0);
        acc[1][0] = __builtin_amdgcn_mfma_f32_16x16x32_bf16(a1, b0, acc[1][0], 0, 0, 0);
        acc[1][1] = __builtin_amdgcn_mfma_f32_16x16x32_bf16(a1, b1, acc[1][1], 0, 0, 0);
        acc[1][2] = __builtin_amdgcn_mfma_f32_16x16x32_bf16(a1, b2, acc[1][2], 0, 0, 0);
        acc[1][3] = __builtin_amdgcn_mfma_f32_16x16x32_bf16(a1, b3, acc[1][3], 0, 0, 0);
        ap0 += 32; ap1 += 32; bp0 += 32; bp1 += 32; bp2 += 32; bp3 += 32;
    }

    const int crow = m0 + wm * 32 + kg * 4;
    const int ccol = n0 + wn * 64 + r;
    #pragma unroll
    for (int ni = 0; ni < 4; ++ni) {
        const float bv = bias[ccol + ni * 16];
        #pragma unroll
        for (int mi = 0; mi < 2; ++mi) {
            #pragma unroll
            for (int jj = 0; jj < 4; ++jj) {
                C[(size_t)(crow + mi * 16 + jj) * ldc + (ccol + ni * 16)] =
                    (bf16_t)(acc[mi][ni][jj] + bv);
            }
        }
    }
}

__global__ __launch_bounds__(256) void k_gemm(
    const bf16_t* __restrict__ A, int lda, const bf16_t* __restrict__ Bt, int ldb,
    const float* __restrict__ bias, bf16_t* __restrict__ C, int ldc,
    int K, int a_thresh, int a_fix)
{
    gemm_body(A, lda, Bt, ldb, bias, C, ldc, blockIdx.y * 64, blockIdx.x * 128, K, a_thresh, a_fix);
}

// combined per-step GEMMs: Hf = h_bf @ UfW + Ufb (N=256) ; iuo = hsum_bf @ UiW + Uib (N=768)
__global__ __launch_bounds__(256) void k_stepg(
    const bf16_t* __restrict__ hbf, const bf16_t* __restrict__ hsum,
    const bf16_t* __restrict__ UfWt, const float* __restrict__ Ufb,
    const bf16_t* __restrict__ UiWt, const float* __restrict__ Uib,
    bf16_t* __restrict__ Hf, bf16_t* __restrict__ iuo)
{
    const int m0 = blockIdx.y * 64;
    if (blockIdx.x < 2)
        gemm_body(hbf, HH, UfWt, HH, Ufb, Hf, HH, m0, blockIdx.x * 128, HH, 1 << 30, 0);
    else
        gemm_body(hsum, HH, UiWt, HH, Uib, iuo, 768, m0, (blockIdx.x - 2) * 128, HH, 1 << 30, 0);
}

// ---------------- embed GEMM: x = concat_s(E[tok_s]) @ lin_W + lin_b  (K=1024, N=256) ----------------
__global__ __launch_bounds__(256) void k_embed(
    const int* __restrict__ tok1, const int* __restrict__ tok2,
    const float* __restrict__ E, const bf16_t* __restrict__ linWt,
    const float* __restrict__ linb, bf16_t* __restrict__ xout)
{
    __shared__ int toff[64][SS];
    const int t = threadIdx.x;
    const int m0 = blockIdx.y * 64;
    const int n0 = blockIdx.x * 128;
    {
        const int lr = t >> 2, s = t & 3;
        const int m = m0 + lr;
        const int e = (m >= LN) ? 1 : 0;
        const int rrow = m - e * LN;
        const int* tok = e ? tok2 : tok1;
        toff[lr][s] = tok[(size_t)rrow * SS + s] * HH;   // element offset into E
    }
    __syncthreads();
    const int lane = t & 63, w = t >> 6;
    const int wm = w >> 1, wn = w & 1;
    const int r = lane & 15, kg = lane >> 4;
    const int lr0 = wm * 32 + r, lr1 = lr0 + 16;
    const bf16_t* bp0 = linWt + (size_t)(n0 + wn * 64 + r) * 1024 + kg * 8;
    const bf16_t* bp1 = bp0 + 16 * 1024;
    const bf16_t* bp2 = bp1 + 16 * 1024;
    const bf16_t* bp3 = bp2 + 16 * 1024;

    const f32x4 zero = {0.f, 0.f, 0.f, 0.f};
    f32x4 acc[2][4];
    #pragma unroll
    for (int mi = 0; mi < 2; ++mi)
        #pragma unroll
        for (int ni = 0; ni < 4; ++ni) acc[mi][ni] = zero;

    for (int k0 = 0; k0 < 1024; k0 += 32) {
        const int kk = k0 + kg * 8;
        const int s = kk >> 8, off = kk & 255;
        const float* a0p = E + (size_t)toff[lr0][s] + off;
        const float* a1p = E + (size_t)toff[lr1][s] + off;
        const float4 u0 = *(const float4*)a0p;
        const float4 u1 = *(const float4*)(a0p + 4);
        const float4 v0 = *(const float4*)a1p;
        const float4 v1 = *(const float4*)(a1p + 4);
        bf16x8 a0, a1;
        a0[0] = (bf16_t)u0.x; a0[1] = (bf16_t)u0.y; a0[2] = (bf16_t)u0.z; a0[3] = (bf16_t)u0.w;
        a0[4] = (bf16_t)u1.x; a0[5] = (bf16_t)u1.y; a0[6] = (bf16_t)u1.z; a0[7] = (bf16_t)u1.w;
        a1[0] = (bf16_t)v0.x; a1[1] = (bf16_t)v0.y; a1[2] = (bf16_t)v0.z; a1[3] = (bf16_t)v0.w;
        a1[4] = (bf16_t)v1.x; a1[5] = (bf16_t)v1.y; a1[6] = (bf16_t)v1.z; a1[7] = (bf16_t)v1.w;
        const bf16x8 b0 = *(const bf16x8*)bp0;
        const bf16x8 b1 = *(const bf16x8*)bp1;
        const bf16x8 b2 = *(const bf16x8*)bp2;
        const bf16x8 b3 = *(const bf16x8*)bp3;
        acc[0][0] = __builtin_amdgcn_mfma_f32_16x16x32_bf16(a0, b0, acc[0][0], 0, 0, 0);
        acc[0][1] = __builtin_amdgcn_mfma_f32_16x16x32_bf16(a0, b1, acc[0][1], 0, 0, 0);
        acc[0][2] = __builtin_amdgcn_mfma_f32_16x16x32_bf16(a0, b2, acc[0][2], 0, 0, 0);
        acc[0][3] = __builtin_amdgcn_mfma_f32_16x16x32_bf16(a0, b3, acc[0][3], 0, 0, 0);
        acc[1][0] = __builtin_amdgcn_mfma_f32_16x16x32_bf16(a1, b0, acc[1][0], 0, 0, 0);
        acc[1][1] = __builtin_amdgcn_mfma_f32_16x16x32_bf16(a1, b1, acc[1][1], 0, 0, 0);
        acc[1][2] = __builtin_amdgcn_mfma_f32_16x16x32_bf16(a1, b2, acc[1][2], 0, 0, 0);
        acc[1][3] = __builtin_amdgcn_mfma_f32_16x16x32_bf16(a1, b3, acc[1][3], 0, 0, 0);
        bp0 += 32; bp1 += 32; bp2 += 32; bp3 += 32;
    }

    const int crow = m0 + wm * 32 + kg * 4;
    const int ccol = n0 + wn * 64 + r;
    #pragma unroll
    for (int ni = 0; ni < 4; ++ni) {
        const float bv = linb[ccol + ni * 16];
        #pragma unroll
        for (int mi = 0; mi < 2; ++mi) {
            #pragma unroll
            for (int jj = 0; jj < 4; ++jj) {
                xout[(size_t)(crow + mi * 16 + jj) * HH + (ccol + ni * 16)] =
                    (bf16_t)(acc[mi][ni][jj] + bv);
            }
        }
    }
}

// ---------------- gather: hsum_bf[g] = bf16( sum_valid h_prev[child] ) ----------------
__global__ __launch_bounds__(256) void k_gather_hsum(
    const float* __restrict__ hprev, const int* __restrict__ idx1,
    const int* __restrict__ idx2, int l, bf16_t* __restrict__ hsum_bf)
{
    __shared__ int child[16][KK];
    const int t = threadIdx.x;
    const int g0 = blockIdx.x * 16;
    if (t < 128) {
        const int rr = t >> 3, k = t & 7;
        const int g = g0 + rr;
        const int e = g >> 11, n = g & (NN - 1);
        const int* idxp = e ? idx2 : idx1;
        const int il = idxp[((size_t)l * NN + n) * KK + k];
        child[rr][k] = (il >= 1) ? (e * NN + il - 1) : -1;
    }
    __syncthreads();
    for (int rr = 0; rr < 16; ++rr) {
        float s = 0.f;
        #pragma unroll
        for (int k = 0; k < KK; ++k) {
            const int ch = child[rr][k];
            if (ch >= 0) s += hprev[(size_t)ch * HH + t];
        }
        hsum_bf[(size_t)(g0 + rr) * HH + t] = (bf16_t)s;
    }
}

// ---------------- gates ----------------
__global__ __launch_bounds__(256) void k_gates(
    const bf16_t* __restrict__ WxBase, int wx_thresh, int wx_fix,
    const bf16_t* __restrict__ iuo,
    const bf16_t* __restrict__ Hf,
    const int* __restrict__ idx1, const int* __restrict__ idx2, int l,
    const float* __restrict__ cprev,
    float* __restrict__ hout, float* __restrict__ cout, bf16_t* __restrict__ hbf)
{
    __shared__ int child[8][KK];
    const int t = threadIdx.x;
    const int g0 = blockIdx.x * 8;
    if (t < 64) {
        const int rr = t >> 3, k = t & 7;
        const int g = g0 + rr;
        const int e = g >> 11, n = g & (NN - 1);
        const int* idxp = e ? idx2 : idx1;
        const int il = idxp[((size_t)l * NN + n) * KK + k];
        child[rr][k] = (il >= 1) ? (e * NN + il - 1) : -1;
    }
    __syncthreads();
    for (int rr = 0; rr < 8; ++rr) {
        const int g = g0 + rr;
        const int wrow = g + (g >= wx_thresh ? wx_fix : 0);
        const bf16_t* wx = WxBase + (size_t)wrow * 1024;
        const float Wf = (float)wx[t];
        const float Wi = (float)wx[256 + t];
        const float Wu = (float)wx[512 + t];
        const float Wo = (float)wx[768 + t];
        float bfa = 0.f;
        #pragma unroll
        for (int k = 0; k < KK; ++k) {
            const int ch = child[rr][k];
            if (ch >= 0) {
                const float fk = sigmoidf_(Wf + (float)Hf[(size_t)ch * HH + t]);
                bfa = fmaf(fk, cprev[(size_t)ch * HH + t], bfa);
            }
        }
        const size_t ib = (size_t)g * 768;
        const float ig = sigmoidf_((float)iuo[ib + t] + Wi);
        const float ug = tanhf((float)iuo[ib + 256 + t] + Wu);
        const float og = sigmoidf_((float)iuo[ib + 512 + t] + Wo);
        const float nc = fmaf(ig, ug, bfa);
        const float nh = og * tanhf(nc);
        hout[(size_t)g * HH + t] = nh;
        cout[(size_t)g * HH + t] = nc;
        hbf[(size_t)g * HH + t] = (bf16_t)nh;
    }
}

// ---------------- siamese head ----------------
__global__ __launch_bounds__(256) void k_final(
    const float* __restrict__ hlast,   // [2N][H]
    const bf16_t* __restrict__ xbf,    // [2][L][N][H]
    const float* __restrict__ dW, const float* __restrict__ db,  // (H,512),(512)
    const float* __restrict__ oW, const float* __restrict__ ob,  // (512,2),(2)
    float* __restrict__ out)           // [N][2]
{
    __shared__ __align__(16) float ad[8][HH];
    __shared__ __align__(16) float xx[8][512];
    const int t = threadIdx.x;
    const int n0 = blockIdx.x * 8;
    const size_t xoff1 = (size_t)(LL - 1) * NN * HH;
    const size_t xoff2 = (size_t)LN * HH + xoff1;
    #pragma unroll
    for (int rr = 0; rr < 8; ++rr) {
        const int n = n0 + rr;
        const float h1 = hlast[(size_t)n * HH + t] + (float)xbf[xoff1 + (size_t)n * HH + t];
        const float h2 = hlast[((size_t)NN + n) * HH + t] + (float)xbf[xoff2 + (size_t)n * HH + t];
        ad[rr][t] = fabsf(h1 - h2);
    }
    __syncthreads();
    float a0[8], a1[8];
    #pragma unroll
    for (int rr = 0; rr < 8; ++rr) { a0[rr] = 0.f; a1[rr] = 0.f; }
    for (int k = 0; k < HH; k += 4) {
        #pragma unroll
        for (int kk = 0; kk < 4; ++kk) {
            const float b0 = dW[(size_t)(k + kk) * 512 + t];
            const float b1 = dW[(size_t)(k + kk) * 512 + 256 + t];
            #pragma unroll
            for (int rr = 0; rr < 8; ++rr) {
                const float av = ad[rr][k + kk];
                a0[rr] = fmaf(av, b0, a0[rr]);
                a1[rr] = fmaf(av, b1, a1[rr]);
            }
        }
    }
    const float db0 = db[t], db1 = db[256 + t];
    #pragma unroll
    for (int rr = 0; rr < 8; ++rr) {
        xx[rr][t] = tanhf(a0[rr] + db0);
        xx[rr][256 + t] = tanhf(a1[rr] + db1);
    }
    __syncthreads();
    const int w = t >> 6, lane = t & 63;
    for (int rr = w; rr < 8; rr += 4) {
        float p0 = 0.f, p1 = 0.f;
        for (int k = lane; k < 512; k += 64) {
            const float xv = xx[rr][k];
            p0 = fmaf(xv, oW[2 * k + 0], p0);
            p1 = fmaf(xv, oW[2 * k + 1], p1);
        }
        #pragma unroll
        for (int off = 32; off > 0; off >>= 1) {
            p0 += __shfl_down(p0, off);
            p1 += __shfl_down(p1, off);
        }
        if (lane == 0) {
            const float l0 = p0 + ob[0], l1 = p1 + ob[1];
            const float mx = fmaxf(l0, l1);
            const float e0 = expf(l0 - mx), e1 = expf(l1 - mx);
            const float inv = 1.f / (e0 + e1);
            out[(size_t)(n0 + rr) * 2 + 0] = e0 * inv;
            out[(size_t)(n0 + rr) * 2 + 1] = e1 * inv;
        }
    }
}

extern "C" void kernel_launch(void* const* d_in, const int* in_sizes, int n_in,
                              void* d_out, int out_size, void* d_ws, size_t ws_size,
                              hipStream_t stream) {
    (void)in_sizes; (void)n_in; (void)out_size;
    const int*   tok1 = (const int*)d_in[0];
    const int*   idx1 = (const int*)d_in[1];
    const int*   tok2 = (const int*)d_in[2];
    const int*   idx2 = (const int*)d_in[3];
    const float* E    = (const float*)d_in[4];
    const float* linW = (const float*)d_in[5];
    const float* linb = (const float*)d_in[6];
    const float* UfW  = (const float*)d_in[7];
    const float* Ufb  = (const float*)d_in[8];
    const float* UiW  = (const float*)d_in[9];
    const float* Uib  = (const float*)d_in[10];
    const float* WW   = (const float*)d_in[11];
    const float* Wb   = (const float*)d_in[12];
    const float* dW   = (const float*)d_in[13];
    const float* db   = (const float*)d_in[14];
    const float* oW   = (const float*)d_in[15];
    const float* ob   = (const float*)d_in[16];
    float* out = (float*)d_out;

    // ws layout (bf16 elems unless noted); full mode needs 156,762,112 B, fallback 64,487,424 B
    const bool full = ws_size >= 156762112ull;
    bf16_t* x_bf  = (bf16_t*)d_ws;                       // 49152*256
    bf16_t* p     = x_bf + (size_t)12582912;
    bf16_t* Wx    = p;  p += full ? (size_t)50331648 : (size_t)4194304;
    bf16_t* hsum  = p;  p += 1048576;
    bf16_t* hbf   = p;  p += 1048576;
    bf16_t* Hf    = p;  p += 1048576;
    bf16_t* iuo   = p;  p += 3145728;
    bf16_t* linWt = p;  p += 262144;                     // (256,1024)
    bf16_t* WWt   = p;  p += 262144;                     // (1024,256)
    bf16_t* UfWt  = p;  p += 65536;                      // (256,256)
    bf16_t* UiWt  = p;  p += 196608;                     // (768,256)
    float*  h0    = (float*)p;
    float*  c0    = h0 + 1048576;
    float*  h1    = c0 + 1048576;
    float*  c1    = h1 + 1048576;

    k_cvt_t<<<1024, 256, 0, stream>>>(linW, linWt, 1024, 256);
    k_cvt_t<<<1024, 256, 0, stream>>>(WW,   WWt,   256, 1024);
    k_cvt_t<<<256,  256, 0, stream>>>(UfW,  UfWt,  256, 256);
    k_cvt_t<<<768,  256, 0, stream>>>(UiW,  UiWt,  256, 768);

    k_embed<<<dim3(2, 768), 256, 0, stream>>>(tok1, tok2, E, linWt, linb, x_bf);

    if (full) {
        // Wx for all steps at once: M=49152, K=256, N=1024
        k_gemm<<<dim3(8, 768), 256, 0, stream>>>(x_bf, HH, WWt, HH, Wb, Wx, 1024, HH, 1 << 30, 0);
    }

    float *hc = h0, *cc = c0, *hn = h1, *cn = c1;
    for (int l = 0; l < LL; ++l) {
        if (!full) {
            // Wx for this step: rows are x[l*N .. l*N+2048) and x[LN+l*N ..)
            k_gemm<<<dim3(8, 64), 256, 0, stream>>>(x_bf + (size_t)l * NN * HH, HH, WWt, HH,
                                                    Wb, Wx, 1024, HH, NN, LN - NN);
        }
        // l==0: idx[0] all -1 -> hsum=0, Hf garbage never gathered (poison-safe)
        k_gather_hsum<<<256, 256, 0, stream>>>(hc, idx1, idx2, l, hsum);
        k_stepg<<<dim3(8, 64), 256, 0, stream>>>(hbf, hsum, UfWt, Ufb, UiWt, Uib, Hf, iuo);
        const bf16_t* wxb = full ? (Wx + (size_t)l * NN * 1024) : Wx;
        k_gates<<<512, 256, 0, stream>>>(wxb, full ? NN : (1 << 30), LN - NN,
                                         iuo, Hf, idx1, idx2, l, cc, hn, cn, hbf);
        float* th = hc; hc = hn; hn = th;
        float* tc = cc; cc = cn; cn = tc;
    }

    k_final<<<NN / 8, 256, 0, stream>>>(hc, x_bf, dW, db, oW, ob, out);
}

// Round 3
// 881.688 us; speedup vs baseline: 4.0748x; 1.4957x over previous
//
#include <hip/hip_runtime.h>

#define LL 12
#define NN 2048
#define KK 8
#define SS 4
#define HH 256
#define LN (LL*NN)
#define VV 50000

typedef __bf16 bf16_t;
typedef __bf16 bf16x8 __attribute__((ext_vector_type(8)));
typedef __bf16 bf16x4v __attribute__((ext_vector_type(4)));
typedef float f32x4 __attribute__((ext_vector_type(4)));

__device__ __forceinline__ float sigmoidf_(float x) { return 1.f / (1.f + expf(-x)); }

// ---------------- E f32 -> bf16 (same layout) ----------------
__global__ __launch_bounds__(256) void k_cvtE(const float* __restrict__ src,
                                              bf16_t* __restrict__ dst, int n4)
{
    int i = blockIdx.x * 256 + threadIdx.x;
    const int stride = gridDim.x * 256;
    for (; i < n4; i += stride) {
        const float4 v = ((const float4*)src)[i];
        bf16x4v o;
        o[0] = (bf16_t)v.x; o[1] = (bf16_t)v.y; o[2] = (bf16_t)v.z; o[3] = (bf16_t)v.w;
        ((bf16x4v*)dst)[i] = o;
    }
}

// ---------------- all weight transposes (f32 (K,N) -> bf16 (N,K)) in one kernel ----------------
__global__ __launch_bounds__(256) void k_cvtW(
    const float* __restrict__ linW, const float* __restrict__ WW,
    const float* __restrict__ UfW, const float* __restrict__ UiW,
    bf16_t* __restrict__ linWt, bf16_t* __restrict__ WWt,
    bf16_t* __restrict__ UfWt, bf16_t* __restrict__ UiWt)
{
    int i = blockIdx.x * 256 + threadIdx.x;      // total 786432
    if (i < 262144) {                            // linW (1024,256) -> (256,1024)
        const int rr = i >> 8, cc = i & 255;
        linWt[(size_t)cc * 1024 + rr] = (bf16_t)linW[i];
        return;
    }
    i -= 262144;
    if (i < 262144) {                            // WW (256,1024) -> (1024,256)
        const int rr = i >> 10, cc = i & 1023;
        WWt[(size_t)cc * 256 + rr] = (bf16_t)WW[i];
        return;
    }
    i -= 262144;
    if (i < 65536) {                             // UfW (256,256) -> (256,256)
        const int rr = i >> 8, cc = i & 255;
        UfWt[(size_t)cc * 256 + rr] = (bf16_t)UfW[i];
        return;
    }
    i -= 65536;
    if (i < 196608) {                            // UiW (256,768) -> (768,256)
        const int rr = i / 768, cc = i - rr * 768;
        UiWt[(size_t)cc * 256 + rr] = (bf16_t)UiW[i];
    }
}

// ---------------- embed GEMM: x = concat_s(Ebf[tok_s]) @ lin_W + lin_b ----------------
// grid 768 blocks, 256 thr = 4 waves (2x2); block tile 64x256, wave tile 32x128.
__global__ __launch_bounds__(256) void k_embed(
    const int* __restrict__ tok1, const int* __restrict__ tok2,
    const bf16_t* __restrict__ Ebf, const bf16_t* __restrict__ linWt,
    const float* __restrict__ linb, bf16_t* __restrict__ xout)
{
    __shared__ int toff[64][SS];
    const int t = threadIdx.x;
    const int m0 = blockIdx.x * 64;
    {
        const int lr = t >> 2, s = t & 3;
        const int m = m0 + lr;
        const int e = (m >= LN) ? 1 : 0;
        const int rrow = m - e * LN;
        const int* tok = e ? tok2 : tok1;
        toff[lr][s] = tok[(size_t)rrow * SS + s] * HH;
    }
    __syncthreads();
    const int lane = t & 63, w = t >> 6;
    const int wm = w >> 1, wn = w & 1;
    const int r = lane & 15, kg = lane >> 4;
    const int lr0 = wm * 32 + r, lr1 = lr0 + 16;
    const bf16_t* bp[8];
    #pragma unroll
    for (int j = 0; j < 8; ++j)
        bp[j] = linWt + (size_t)(wn * 128 + j * 16 + r) * 1024 + kg * 8;

    const f32x4 zero = {0.f, 0.f, 0.f, 0.f};
    f32x4 acc[2][8];
    #pragma unroll
    for (int mi = 0; mi < 2; ++mi)
        #pragma unroll
        for (int j = 0; j < 8; ++j) acc[mi][j] = zero;

    for (int k0 = 0; k0 < 1024; k0 += 32) {
        const int s = k0 >> 8, off = (k0 & 255) + kg * 8;
        const bf16x8 a0 = *(const bf16x8*)(Ebf + (size_t)toff[lr0][s] + off);
        const bf16x8 a1 = *(const bf16x8*)(Ebf + (size_t)toff[lr1][s] + off);
        #pragma unroll
        for (int j = 0; j < 8; ++j) {
            const bf16x8 b = *(const bf16x8*)bp[j];
            acc[0][j] = __builtin_amdgcn_mfma_f32_16x16x32_bf16(a0, b, acc[0][j], 0, 0, 0);
            acc[1][j] = __builtin_amdgcn_mfma_f32_16x16x32_bf16(a1, b, acc[1][j], 0, 0, 0);
            bp[j] += 32;
        }
    }
    const int crow = m0 + wm * 32 + kg * 4;
    #pragma unroll
    for (int j = 0; j < 8; ++j) {
        const int ccol = wn * 128 + j * 16 + r;
        const float bv = linb[ccol];
        #pragma unroll
        for (int mi = 0; mi < 2; ++mi)
            #pragma unroll
            for (int jj = 0; jj < 4; ++jj)
                xout[(size_t)(crow + mi * 16 + jj) * HH + ccol] =
                    (bf16_t)(acc[mi][j][jj] + bv);
    }
}

// ---------------- per-step fused GEMMs ----------------
// grid (2,128), 512 thr = 8 waves; 32 rows/block; wave col-tile 128.
// col-tiles ct: 0-1 -> Hf = hbf@UfW+Ufb ; 2-7 -> iuo = hsum@UiW+Uib ; 8-15 -> Wx = x@WW+Wb.
// hsum gathered once into LDS (rotate-swizzled, 2-way-free ds_read_b128).
__global__ __launch_bounds__(512) void k_step1(
    const bf16_t* __restrict__ xbf, const bf16_t* __restrict__ hbf,
    const int* __restrict__ idx1, const int* __restrict__ idx2, const int l,
    const bf16_t* __restrict__ UfWt, const float* __restrict__ Ufb,
    const bf16_t* __restrict__ UiWt, const float* __restrict__ Uib,
    const bf16_t* __restrict__ WWt, const float* __restrict__ Wb,
    bf16_t* __restrict__ Hf, bf16_t* __restrict__ iuo, bf16_t* __restrict__ Wxs)
{
    __shared__ __align__(16) ushort hs[32 * 256];   // 16 KB: 32 rows x 512 B, swizzled
    const int t = threadIdx.x;
    const int g0 = blockIdx.y * 32;
    const int e = g0 >> 11;            // block-uniform (32 | 2048)
    const int n0 = g0 & (NN - 1);
    const int half = blockIdx.x;       // 0: Hf+iuo (needs gather), 1: Wx

    if (half == 0) {
        const int rr = t >> 4, q = t & 15;
        const int* idxp = (e ? idx2 : idx1) + ((size_t)l * NN + n0 + rr) * KK;
        int ch[KK];
        #pragma unroll
        for (int k = 0; k < KK; ++k) {
            const int il = idxp[k];
            ch[k] = (il >= 1) ? (e * NN + il - 1) : -1;
        }
        #pragma unroll
        for (int h16 = 0; h16 < 2; ++h16) {
            const int s = q + h16 * 16;             // 16B slice index 0..31
            float acc[8] = {0, 0, 0, 0, 0, 0, 0, 0};
            #pragma unroll
            for (int k = 0; k < KK; ++k) {
                if (ch[k] >= 0) {
                    const bf16x8 v = *(const bf16x8*)(hbf + (size_t)ch[k] * HH + s * 8);
                    #pragma unroll
                    for (int j = 0; j < 8; ++j) acc[j] += (float)v[j];
                }
            }
            bf16x8 o;
            #pragma unroll
            for (int j = 0; j < 8; ++j) o[j] = (bf16_t)acc[j];
            const int ss = (s + 4 * rr) & 31;       // rotate swizzle
            *(bf16x8*)((char*)hs + rr * 512 + ss * 16) = o;
        }
    }
    __syncthreads();

    const int lane = t & 63, w = t >> 6;
    const int ct = half * 8 + w;
    const int r = lane & 15, kg = lane >> 4;

    const bf16_t* Bt; int bn0; const float* bias; bf16_t* Cout; int ldc;
    if (ct < 2)      { Bt = UfWt; bn0 = ct * 128;       bias = Ufb; Cout = Hf;  ldc = HH;   }
    else if (ct < 8) { Bt = UiWt; bn0 = (ct - 2) * 128; bias = Uib; Cout = iuo; ldc = 768;  }
    else             { Bt = WWt;  bn0 = (ct - 8) * 128; bias = Wb;  Cout = Wxs; ldc = 1024; }

    const bf16_t* bp[8];
    #pragma unroll
    for (int j = 0; j < 8; ++j)
        bp[j] = Bt + (size_t)(bn0 + j * 16 + r) * HH + kg * 8;

    const f32x4 zero = {0.f, 0.f, 0.f, 0.f};
    f32x4 acc[2][8];
    #pragma unroll
    for (int mi = 0; mi < 2; ++mi)
        #pragma unroll
        for (int j = 0; j < 8; ++j) acc[mi][j] = zero;

    if (ct >= 2 && ct < 8) {
        for (int k0 = 0; k0 < HH; k0 += 32) {
            const int ss = ((k0 >> 3) + kg + 4 * r) & 31;
            const bf16x8 a0 = *(const bf16x8*)((char*)hs + r * 512 + ss * 16);
            const bf16x8 a1 = *(const bf16x8*)((char*)hs + (r + 16) * 512 + ss * 16);
            #pragma unroll
            for (int j = 0; j < 8; ++j) {
                const bf16x8 b = *(const bf16x8*)bp[j];
                acc[0][j] = __builtin_amdgcn_mfma_f32_16x16x32_bf16(a0, b, acc[0][j], 0, 0, 0);
                acc[1][j] = __builtin_amdgcn_mfma_f32_16x16x32_bf16(a1, b, acc[1][j], 0, 0, 0);
                bp[j] += 32;
            }
        }
    } else {
        const bf16_t* abase = (ct < 2)
            ? (hbf + (size_t)g0 * HH)
            : (xbf + ((size_t)e * LN + (size_t)l * NN + n0) * HH);
        const bf16_t* ap0 = abase + (size_t)r * HH + kg * 8;
        const bf16_t* ap1 = abase + (size_t)(r + 16) * HH + kg * 8;
        for (int k0 = 0; k0 < HH; k0 += 32) {
            const bf16x8 a0 = *(const bf16x8*)ap0;
            const bf16x8 a1 = *(const bf16x8*)ap1;
            ap0 += 32; ap1 += 32;
            #pragma unroll
            for (int j = 0; j < 8; ++j) {
                const bf16x8 b = *(const bf16x8*)bp[j];
                acc[0][j] = __builtin_amdgcn_mfma_f32_16x16x32_bf16(a0, b, acc[0][j], 0, 0, 0);
                acc[1][j] = __builtin_amdgcn_mfma_f32_16x16x32_bf16(a1, b, acc[1][j], 0, 0, 0);
                bp[j] += 32;
            }
        }
    }

    const int crow = g0 + kg * 4;
    #pragma unroll
    for (int j = 0; j < 8; ++j) {
        const int ccol = bn0 + j * 16 + r;
        const float bv = bias[ccol];
        #pragma unroll
        for (int mi = 0; mi < 2; ++mi)
            #pragma unroll
            for (int jj = 0; jj < 4; ++jj)
                Cout[(size_t)(crow + mi * 16 + jj) * ldc + ccol] =
                    (bf16_t)(acc[mi][j][jj] + bv);
    }
}

// ---------------- gates ----------------
__global__ __launch_bounds__(256) void k_gates(
    const bf16_t* __restrict__ Wxs, const bf16_t* __restrict__ iuo,
    const bf16_t* __restrict__ Hf,
    const int* __restrict__ idx1, const int* __restrict__ idx2, const int l,
    const float* __restrict__ cprev, float* __restrict__ cnext,
    bf16_t* __restrict__ hbf)
{
    __shared__ int child[8][KK];
    const int t = threadIdx.x;
    const int g0 = blockIdx.x * 8;
    if (t < 64) {
        const int rr = t >> 3, k = t & 7;
        const int g = g0 + rr;
        const int e = g >> 11, n = g & (NN - 1);
        const int* idxp = e ? idx2 : idx1;
        const int il = idxp[((size_t)l * NN + n) * KK + k];
        child[rr][k] = (il >= 1) ? (e * NN + il - 1) : -1;
    }
    __syncthreads();
    for (int rr = 0; rr < 8; ++rr) {
        const int g = g0 + rr;
        const bf16_t* wx = Wxs + (size_t)g * 1024;
        const float Wf = (float)wx[t];
        const float Wi = (float)wx[256 + t];
        const float Wu = (float)wx[512 + t];
        const float Wo = (float)wx[768 + t];
        float bfa = 0.f;
        #pragma unroll
        for (int k = 0; k < KK; ++k) {
            const int ch = child[rr][k];
            if (ch >= 0) {
                const float fk = sigmoidf_(Wf + (float)Hf[(size_t)ch * HH + t]);
                bfa = fmaf(fk, cprev[(size_t)ch * HH + t], bfa);
            }
        }
        const size_t ib = (size_t)g * 768;
        const float ig = sigmoidf_((float)iuo[ib + t] + Wi);
        const float ug = tanhf((float)iuo[ib + 256 + t] + Wu);
        const float og = sigmoidf_((float)iuo[ib + 512 + t] + Wo);
        const float nc = fmaf(ig, ug, bfa);
        const float nh = og * tanhf(nc);
        cnext[(size_t)g * HH + t] = nc;
        hbf[(size_t)g * HH + t] = (bf16_t)nh;
    }
}

// ---------------- siamese head ----------------
__global__ __launch_bounds__(256) void k_final(
    const bf16_t* __restrict__ hlast,  // [2N][H] bf16
    const bf16_t* __restrict__ xbf,    // [2][L][N][H]
    const float* __restrict__ dW, const float* __restrict__ db,
    const float* __restrict__ oW, const float* __restrict__ ob,
    float* __restrict__ out)           // [N][2]
{
    __shared__ __align__(16) float ad[8][HH];
    __shared__ __align__(16) float xx[8][512];
    const int t = threadIdx.x;
    const int n0 = blockIdx.x * 8;
    const size_t xoff1 = (size_t)(LL - 1) * NN * HH;
    const size_t xoff2 = (size_t)LN * HH + xoff1;
    #pragma unroll
    for (int rr = 0; rr < 8; ++rr) {
        const int n = n0 + rr;
        const float h1 = (float)hlast[(size_t)n * HH + t] + (float)xbf[xoff1 + (size_t)n * HH + t];
        const float h2 = (float)hlast[((size_t)NN + n) * HH + t] + (float)xbf[xoff2 + (size_t)n * HH + t];
        ad[rr][t] = fabsf(h1 - h2);
    }
    __syncthreads();
    float a0[8], a1[8];
    #pragma unroll
    for (int rr = 0; rr < 8; ++rr) { a0[rr] = 0.f; a1[rr] = 0.f; }
    for (int k = 0; k < HH; k += 4) {
        #pragma unroll
        for (int kk = 0; kk < 4; ++kk) {
            const float b0 = dW[(size_t)(k + kk) * 512 + t];
            const float b1 = dW[(size_t)(k + kk) * 512 + 256 + t];
            #pragma unroll
            for (int rr = 0; rr < 8; ++rr) {
                const float av = ad[rr][k + kk];
                a0[rr] = fmaf(av, b0, a0[rr]);
                a1[rr] = fmaf(av, b1, a1[rr]);
            }
        }
    }
    const float db0 = db[t], db1 = db[256 + t];
    #pragma unroll
    for (int rr = 0; rr < 8; ++rr) {
        xx[rr][t] = tanhf(a0[rr] + db0);
        xx[rr][256 + t] = tanhf(a1[rr] + db1);
    }
    __syncthreads();
    const int w = t >> 6, lane = t & 63;
    for (int rr = w; rr < 8; rr += 4) {
        float p0 = 0.f, p1 = 0.f;
        for (int k = lane; k < 512; k += 64) {
            const float xv = xx[rr][k];
            p0 = fmaf(xv, oW[2 * k + 0], p0);
            p1 = fmaf(xv, oW[2 * k + 1], p1);
        }
        #pragma unroll
        for (int off = 32; off > 0; off >>= 1) {
            p0 += __shfl_down(p0, off);
            p1 += __shfl_down(p1, off);
        }
        if (lane == 0) {
            const float l0 = p0 + ob[0], l1 = p1 + ob[1];
            const float mx = fmaxf(l0, l1);
            const float e0 = expf(l0 - mx), e1 = expf(l1 - mx);
            const float inv = 1.f / (e0 + e1);
            out[(size_t)(n0 + rr) * 2 + 0] = e0 * inv;
            out[(size_t)(n0 + rr) * 2 + 1] = e1 * inv;
        }
    }
}

extern "C" void kernel_launch(void* const* d_in, const int* in_sizes, int n_in,
                              void* d_out, int out_size, void* d_ws, size_t ws_size,
                              hipStream_t stream) {
    (void)in_sizes; (void)n_in; (void)out_size; (void)ws_size;
    const int*   tok1 = (const int*)d_in[0];
    const int*   idx1 = (const int*)d_in[1];
    const int*   tok2 = (const int*)d_in[2];
    const int*   idx2 = (const int*)d_in[3];
    const float* E    = (const float*)d_in[4];
    const float* linW = (const float*)d_in[5];
    const float* linb = (const float*)d_in[6];
    const float* UfW  = (const float*)d_in[7];
    const float* Ufb  = (const float*)d_in[8];
    const float* UiW  = (const float*)d_in[9];
    const float* Uib  = (const float*)d_in[10];
    const float* WW   = (const float*)d_in[11];
    const float* Wb   = (const float*)d_in[12];
    const float* dW   = (const float*)d_in[13];
    const float* db   = (const float*)d_in[14];
    const float* oW   = (const float*)d_in[15];
    const float* ob   = (const float*)d_in[16];
    float* out = (float*)d_out;

    // ws layout (bf16 elems). xbf | UNION{ Ebf (dead after embed) | step buffers } | weights
    bf16_t* xbf = (bf16_t*)d_ws;                       // 12,582,912 elems
    bf16_t* uni = xbf + (size_t)12582912;
    bf16_t* Ebf = uni;                                 // 12,800,000 elems (25.6 MB)
    bf16_t* Wxs = uni;                                 // 4,194,304
    bf16_t* iuo = Wxs + (size_t)4194304;               // 3,145,728
    bf16_t* Hf  = iuo + (size_t)3145728;               // 1,048,576
    bf16_t* hbf = Hf  + (size_t)1048576;               // 1,048,576
    float*  c0  = (float*)(hbf + (size_t)1048576);     // 1,048,576 f32
    float*  c1  = c0 + (size_t)1048576;
    // union end: max(25,600,000 B , 27,262,976 B) = 27,262,976 B -> 13,631,488 bf16 elems
    bf16_t* wts   = uni + (size_t)13631488;
    bf16_t* linWt = wts;                               // 262,144 (256,1024)
    bf16_t* WWt   = linWt + (size_t)262144;            // 262,144 (1024,256)
    bf16_t* UfWt  = WWt   + (size_t)262144;            // 65,536  (256,256)
    bf16_t* UiWt  = UfWt  + (size_t)65536;             // 196,608 (768,256)

    k_cvtE<<<2048, 256, 0, stream>>>(E, Ebf, VV * HH / 4);
    k_cvtW<<<3072, 256, 0, stream>>>(linW, WW, UfW, UiW, linWt, WWt, UfWt, UiWt);

    k_embed<<<768, 256, 0, stream>>>(tok1, tok2, Ebf, linWt, linb, xbf);

    float *cc = c0, *cn = c1;
    for (int l = 0; l < LL; ++l) {
        // l==0: idx[0] all -1 -> hsum=0, children never read (stale hbf/c safe)
        k_step1<<<dim3(2, 128), 512, 0, stream>>>(xbf, hbf, idx1, idx2, l,
                                                  UfWt, Ufb, UiWt, Uib, WWt, Wb,
                                                  Hf, iuo, Wxs);
        k_gates<<<512, 256, 0, stream>>>(Wxs, iuo, Hf, idx1, idx2, l, cc, cn, hbf);
        float* tc = cc; cc = cn; cn = tc;
    }

    k_final<<<NN / 8, 256, 0, stream>>>(hbf, xbf, dW, db, oW, ob, out);
}